// Round 1
// baseline (632.712 us; speedup 1.0000x reference)
//
#include <hip/hip_runtime.h>
#include <math.h>

// B=512, H=W=14, DIN=512, EDIM=64, K=256, GRID=2 -> 2048 tokens, 128 hidden
#define N_TOKENS   2048
#define DECODED_SZ 51380224   // 512*14*14*512
// d_out layout: [decoded (51380224)][perplexity (1)][commitment (1)][indices (2048)]

typedef __attribute__((ext_vector_type(8)))  short bf16x8;
typedef __attribute__((ext_vector_type(16))) float f32x16;
typedef __attribute__((ext_vector_type(4)))  unsigned int u32x4;

__device__ __forceinline__ float gelu_exact(float x) {
    return 0.5f * x * (1.0f + erff(x * 0.70710678118654752440f));
}

// round-to-nearest-even fp32 -> bf16 bits
__device__ __forceinline__ unsigned int f2bf(float x) {
    unsigned int u = __float_as_uint(x);
    return (u + 0x7fffu + ((u >> 16) & 1u)) >> 16;
}
__device__ __forceinline__ float bf2f(unsigned int b) {
    return __uint_as_float(b << 16);
}

// packed fp32x2 -> bf16x2 (lo=src0, hi=src1), RNE via HW
__device__ __forceinline__ unsigned int cvt_pk_bf16(float a, float b) {
    unsigned int p;
    asm("v_cvt_pk_bf16_f32 %0, %1, %2" : "=v"(p) : "v"(a), "v"(b));
    return p;
}
// split pair into hi word + lo(residual) word
__device__ __forceinline__ void split_pair(float a, float b,
                                           unsigned int& hi, unsigned int& lo) {
    hi = cvt_pk_bf16(a, b);
    const float ra = a - __uint_as_float(hi << 16);
    const float rb = b - __uint_as_float(hi & 0xffff0000u);
    lo = cvt_pk_bf16(ra, rb);
}

union UF { u32x4 u; bf16x8 v; };

// ---------------------------------------------------------------------------
// K0: split w1 [512k x 128n] fp32 into bf16 hi/lo, transposed + k-chunk-blocked
// for direct B-fragment loads: Bt[kc(16)][n(128)][k(32)] bf16.
// 8192 threads: i = n*64 + kg8 (kg8 = group of 8 consecutive k).
// ---------------------------------------------------------------------------
__global__ __launch_bounds__(256) void k0_prep_w1(
    const float* __restrict__ w1,
    unsigned short* __restrict__ bth, unsigned short* __restrict__ btl)
{
    const int i  = blockIdx.x * 256 + threadIdx.x;   // 0..8191
    const int n  = i >> 6;
    const int kg = i & 63;
    const int k0i = kg * 8;

    unsigned int h[8], lo[8];
#pragma unroll
    for (int j = 0; j < 8; ++j) {
        float v = w1[(k0i + j) * 128 + n];
        h[j]  = f2bf(v);
        lo[j] = f2bf(v - bf2f(h[j]));
    }
    const int idx = (k0i >> 5) * 4096 + n * 32 + (k0i & 31);
    uint4 hv, lv;
    hv.x = h[0]  | (h[1] << 16);  hv.y = h[2]  | (h[3] << 16);
    hv.z = h[4]  | (h[5] << 16);  hv.w = h[6]  | (h[7] << 16);
    lv.x = lo[0] | (lo[1] << 16); lv.y = lo[2] | (lo[3] << 16);
    lv.z = lo[4] | (lo[5] << 16); lv.w = lo[6] | (lo[7] << 16);
    *reinterpret_cast<uint4*>(bth + idx) = hv;
    *reinterpret_cast<uint4*>(btl + idx) = lv;
}

// ---------------------------------------------------------------------------
// K1 (v2, register-direct): pooled_h[b*4+tk][128] = mean gelu(delta@enc_w1+b1)
// No LDS staging, no main-loop barriers. Each lane loads its own MFMA
// fragments straight from global:
//   - B from k0-prepped bth/btl (fragment-shaped, 256 KB -> L2 resident)
//   - A from t0/t1 (rows fully consumed per kc; wn-duplicate read hits L1/L2)
// fp32->bf16 hi/lo split in-register via v_cvt_pk_bf16_f32.
// One block per image, 256 thr = 4 waves. M padded 196->256 (8 tiles of 32),
// N=128 (4 tiles), K=512 chunked by 32.
// Wave (wm = w>>1, wn = w&1): M-tiles [wm*4, +4), N-tiles [wn*2, +2).
// ---------------------------------------------------------------------------
__global__ __launch_bounds__(256, 2) void k1_enc_pool(
    const float* __restrict__ t0, const float* __restrict__ t1,
    const unsigned short* __restrict__ bth, const unsigned short* __restrict__ btl,
    const float* __restrict__ b1,
    float* __restrict__ pooled)
{
    __shared__ float sR[2 * 4 * 128];          // 4 KB  (wm, tok, col)

    const int t = threadIdx.x;
    const int b = blockIdx.x;
    const int l     = t & 63;
    const int w     = t >> 6;
    const int wm    = w >> 1;
    const int wn    = w & 1;
    const int lan31 = l & 31;
    const int h     = l >> 5;

    const float4* __restrict__ t0v = reinterpret_cast<const float4*>(t0);
    const float4* __restrict__ t1v = reinterpret_cast<const float4*>(t1);

    f32x16 acc[4][2] = {};

    // per-lane A base (float4 units) and validity per mi-tile
    int gbase[4];
    int valid[4];
#pragma unroll
    for (int mi = 0; mi < 4; ++mi) {
        const int row = (wm * 4 + mi) * 32 + lan31;
        valid[mi] = (row < 196);
        gbase[mi] = (b * 196 + (row < 196 ? row : 0)) * 128 + h * 2;
    }
    // per-lane B fragment offsets (in shorts, within one kc slab of 4096)
    int boff[2][2];
#pragma unroll
    for (int ni = 0; ni < 2; ++ni) {
        const int col = (wn * 2 + ni) * 32 + lan31;
#pragma unroll
        for (int ks = 0; ks < 2; ++ks)
            boff[ni][ks] = col * 32 + ks * 16 + h * 8;
    }

#pragma unroll 1
    for (int kc = 0; kc < 16; ++kc) {
        // ---- B fragments straight from global (L2-resident)
        bf16x8 bh[2][2], bl[2][2];
#pragma unroll
        for (int ni = 0; ni < 2; ++ni)
#pragma unroll
            for (int ks = 0; ks < 2; ++ks) {
                bh[ni][ks] = *reinterpret_cast<const bf16x8*>(
                    bth + kc * 4096 + boff[ni][ks]);
                bl[ni][ks] = *reinterpret_cast<const bf16x8*>(
                    btl + kc * 4096 + boff[ni][ks]);
            }

        // ---- A fragments: load, delta, hi/lo split, MFMA
#pragma unroll
        for (int mi = 0; mi < 4; ++mi) {
            const int mt = wm * 4 + mi;
            if (mt < 7) {                       // mt==7: rows 224..255 all pad
#pragma unroll
                for (int ks = 0; ks < 2; ++ks) {
                    float d0, d1, d2, d3, d4, d5, d6, d7;
                    if (valid[mi]) {
                        const int g = gbase[mi] + kc * 8 + ks * 4;
                        const float4 x0 = t1v[g],     y0 = t0v[g];
                        const float4 x1 = t1v[g + 1], y1 = t0v[g + 1];
                        d0 = x0.x - y0.x; d1 = x0.y - y0.y;
                        d2 = x0.z - y0.z; d3 = x0.w - y0.w;
                        d4 = x1.x - y1.x; d5 = x1.y - y1.y;
                        d6 = x1.z - y1.z; d7 = x1.w - y1.w;
                    } else {
                        d0 = d1 = d2 = d3 = d4 = d5 = d6 = d7 = 0.0f;
                    }
                    UF ah, al;
                    {
                        unsigned int hw, lw;
                        split_pair(d0, d1, hw, lw); ah.u[0] = hw; al.u[0] = lw;
                        split_pair(d2, d3, hw, lw); ah.u[1] = hw; al.u[1] = lw;
                        split_pair(d4, d5, hw, lw); ah.u[2] = hw; al.u[2] = lw;
                        split_pair(d6, d7, hw, lw); ah.u[3] = hw; al.u[3] = lw;
                    }
#pragma unroll
                    for (int ni = 0; ni < 2; ++ni) {
                        acc[mi][ni] = __builtin_amdgcn_mfma_f32_32x32x16_bf16(
                            ah.v, bh[ni][ks], acc[mi][ni], 0, 0, 0);
                        acc[mi][ni] = __builtin_amdgcn_mfma_f32_32x32x16_bf16(
                            ah.v, bl[ni][ks], acc[mi][ni], 0, 0, 0);
                        acc[mi][ni] = __builtin_amdgcn_mfma_f32_32x32x16_bf16(
                            al.v, bh[ni][ks], acc[mi][ni], 0, 0, 0);
                    }
                }
            }
        }
    }

    // ---- epilogue: bias + gelu + pool per token, per lane
    float tokacc[2][4] = {};
#pragma unroll
    for (int ni = 0; ni < 2; ++ni) {
        const int col = (wn * 2 + ni) * 32 + lan31;
        const float bias = b1[col];
#pragma unroll
        for (int mi = 0; mi < 4; ++mi) {
#pragma unroll
            for (int reg = 0; reg < 16; ++reg) {
                const int row = (wm * 4 + mi) * 32 + (reg & 3) + 8 * (reg >> 2) + 4 * h;
                if (row < 196) {
                    const float v = gelu_exact(acc[mi][ni][reg] + bias);
                    const int py = row / 14, px = row % 14;
                    const int tok = ((py >= 7) ? 2 : 0) + ((px >= 7) ? 1 : 0);
                    tokacc[ni][tok] += v;
                }
            }
        }
    }
    // fold h=1 lanes into h=0 lanes
#pragma unroll
    for (int ni = 0; ni < 2; ++ni)
#pragma unroll
        for (int tok = 0; tok < 4; ++tok)
            tokacc[ni][tok] += __shfl_xor(tokacc[ni][tok], 32);
    if (h == 0) {
#pragma unroll
        for (int ni = 0; ni < 2; ++ni)
#pragma unroll
            for (int tok = 0; tok < 4; ++tok)
                sR[(wm * 4 + tok) * 128 + wn * 64 + ni * 32 + lan31] = tokacc[ni][tok];
    }
    __syncthreads();
    for (int i = t; i < 512; i += 256) {
        const int tok = i >> 7, col = i & 127;
        pooled[(b * 4 + tok) * 128 + col] =
            (sR[tok * 128 + col] + sR[(4 + tok) * 128 + col]) * (1.0f / 49.0f);
    }
}

// ---------------------------------------------------------------------------
// K2: per-token middle. 512 blocks x 256 thr, 4 tokens/block.
// Codebook staged in LDS (stride 66 -> conflict-free float2 reads).
// ---------------------------------------------------------------------------
__global__ __launch_bounds__(256, 2) void k2_mid(
    const float* __restrict__ pooled,
    const float* __restrict__ w2,  const float* __restrict__ b2,
    const float* __restrict__ cb,
    const float* __restrict__ dw1, const float* __restrict__ db1,
    const float* __restrict__ dw2, const float* __restrict__ db2,
    float* __restrict__ dec, float* __restrict__ hist, float* __restrict__ commit,
    float* __restrict__ out_idx)
{
    __shared__ float sCB[256 * 66];  // 67.6 KB codebook, padded stride
    __shared__ float ph[4 * 128];
    __shared__ float es[4 * 64];
    __shared__ float hd[4 * 128];
    __shared__ float rd[256];
    __shared__ int   ri[256];
    __shared__ int   idxs[4];
    __shared__ float dms[4];

    const int t   = threadIdx.x;
    const int tk0 = blockIdx.x * 4;

    if (t < 128)
        reinterpret_cast<float4*>(ph)[t] =
            reinterpret_cast<const float4*>(pooled + tk0 * 128)[t];
    for (int i = t; i < 16384; i += 256) {
        int row = i >> 6, k = i & 63;
        sCB[row * 66 + k] = cb[i];
    }
    __syncthreads();

    // e = ph @ w2 + b2   (j = t&63, one token per 64-lane group)
    {
        const int j = t & 63, tok = t >> 6;
        float a = b2[j];
        const float* phr = ph + tok * 128;
#pragma unroll 8
        for (int k = 0; k < 128; ++k)
            a = fmaf(phr[k], w2[k * 64 + j], a);
        es[tok * 64 + j] = a;
    }
    __syncthreads();

    // VQ: 64 threads/token, 4 strided codes each; explicit index tiebreak
    {
        const int tok = t >> 6, c8 = t & 63;
        float2 ev[32];
#pragma unroll
        for (int k = 0; k < 32; ++k)
            ev[k] = *reinterpret_cast<const float2*>(es + tok * 64 + 2 * k);
        float dmin = 3.4e38f; int imin = 0;
#pragma unroll
        for (int cc = 0; cc < 4; ++cc) {
            const int c = c8 + cc * 64;
            const float* cr = sCB + c * 66;
            float d = 0.f;
#pragma unroll
            for (int k = 0; k < 32; ++k) {
                float2 c2 = *reinterpret_cast<const float2*>(cr + 2 * k);
                float d0 = ev[k].x - c2.x;
                float d1 = ev[k].y - c2.y;
                d = fmaf(d0, d0, d);
                d = fmaf(d1, d1, d);
            }
            if (d < dmin || (d == dmin && c < imin)) { dmin = d; imin = c; }
        }
        rd[t] = dmin; ri[t] = imin;
    }
    __syncthreads();
    for (int s = 32; s > 0; s >>= 1) {
        if ((t & 63) < s) {
            float dn = rd[t + s]; int in = ri[t + s];
            if (dn < rd[t] || (dn == rd[t] && in < ri[t])) { rd[t] = dn; ri[t] = in; }
        }
        __syncthreads();
    }
    if ((t & 63) == 0) {
        const int tok = t >> 6;
        idxs[tok] = ri[t];
        dms[tok]  = rd[t];
        out_idx[tk0 + tok] = (float)ri[t];
        atomicAdd(&hist[ri[t]], 1.0f);
    }
    __syncthreads();
    if (t == 0) {
        float s = dms[0] + dms[1] + dms[2] + dms[3];
        atomicAdd(commit, s);
    }

    // hd = gelu(q @ dw1 + db1), q read straight from sCB
    {
        const int j = t & 127, half = t >> 7;
        const float bj = db1[j];
        float a0 = bj, a1 = bj;
        const float* q0 = sCB + idxs[half * 2 + 0] * 66;
        const float* q1 = sCB + idxs[half * 2 + 1] * 66;
#pragma unroll 4
        for (int k = 0; k < 64; ++k) {
            const float wv = dw1[k * 128 + j];
            a0 = fmaf(q0[k], wv, a0);
            a1 = fmaf(q1[k], wv, a1);
        }
        hd[(half * 2 + 0) * 128 + j] = gelu_exact(a0);
        hd[(half * 2 + 1) * 128 + j] = gelu_exact(a1);
    }
    __syncthreads();

    // dec = hd @ dw2 + db2  (each thread: cols t and t+256, all 4 tokens)
    {
        float a0[4], a1[4];
        const float bb0 = db2[t], bb1 = db2[t + 256];
#pragma unroll
        for (int q = 0; q < 4; ++q) { a0[q] = bb0; a1[q] = bb1; }
#pragma unroll 2
        for (int j = 0; j < 128; ++j) {
            const float w0 = dw2[j * 512 + t];
            const float w1v = dw2[j * 512 + 256 + t];
#pragma unroll
            for (int q = 0; q < 4; ++q) {
                const float h = hd[q * 128 + j];
                a0[q] = fmaf(h, w0, a0[q]);
                a1[q] = fmaf(h, w1v, a1[q]);
            }
        }
#pragma unroll
        for (int q = 0; q < 4; ++q) {
            dec[(tk0 + q) * 512 + t]       = a0[q];
            dec[(tk0 + q) * 512 + 256 + t] = a1[q];
        }
    }
}

// ---------------------------------------------------------------------------
// K2b: finalize perplexity + commitment (1 block)
// ---------------------------------------------------------------------------
__global__ __launch_bounds__(256) void k2b_final(
    const float* __restrict__ hist, const float* __restrict__ commit,
    float* __restrict__ out2)
{
    __shared__ float red[256];
    const int t = threadIdx.x;
    float p = hist[t] * (1.0f / 2048.0f);
    red[t] = p * logf(p + 1e-10f);
    __syncthreads();
    for (int s = 128; s > 0; s >>= 1) {
        if (t < s) red[t] += red[t + s];
        __syncthreads();
    }
    if (t == 0) {
        out2[0] = expf(-red[0]);
        out2[1] = commit[0] * (1.0f / 131072.0f);   // /(2048*64)
    }
}

// ---------------------------------------------------------------------------
// K3: bilinear upsample dec[B,2,2,512] -> decoded[B,14,14,512]
// Weights/offsets precomputed once per block into LDS.
// ---------------------------------------------------------------------------
__global__ __launch_bounds__(256, 4) void k3_upsample(
    const float* __restrict__ dec, float* __restrict__ out)
{
    __shared__ float  sdec[4 * 512];
    __shared__ float4 wts[196];
    __shared__ int4   offs[196];
    const int b = blockIdx.x, t = threadIdx.x;

    for (int i = t; i < 512; i += 256)
        reinterpret_cast<float4*>(sdec)[i] =
            reinterpret_cast<const float4*>(dec + b * 2048)[i];
    if (t < 196) {
        const int y = t / 14, x = t % 14;
        const float sy = (y + 0.5f) * (1.0f / 7.0f) - 0.5f;
        const float sx = (x + 0.5f) * (1.0f / 7.0f) - 0.5f;
        const int iy = (int)floorf(sy), ix = (int)floorf(sx);
        const float fy = sy - (float)iy, fx = sx - (float)ix;
        const int y0 = min(max(iy, 0), 1), y1 = min(max(iy + 1, 0), 1);
        const int x0 = min(max(ix, 0), 1), x1 = min(max(ix + 1, 0), 1);
        float4 w;
        w.x = (1.f - fy) * (1.f - fx); w.y = (1.f - fy) * fx;
        w.z = fy * (1.f - fx);         w.w = fy * fx;
        wts[t] = w;
        int4 o;
        o.x = (y0 * 2 + x0) * 128; o.y = (y0 * 2 + x1) * 128;
        o.z = (y1 * 2 + x0) * 128; o.w = (y1 * 2 + x1) * 128;
        offs[t] = o;
    }
    __syncthreads();

    const float4* s4 = reinterpret_cast<const float4*>(sdec);
    float4* o4 = reinterpret_cast<float4*>(out) + b * 25088;
    const int c4 = t & 127, ph2 = t >> 7;

#pragma unroll 2
    for (int it = 0; it < 98; ++it) {
        const int pos = ph2 + it * 2;
        const float4 w = wts[pos];
        const int4   o = offs[pos];
        const float4 v00 = s4[o.x + c4];
        const float4 v01 = s4[o.y + c4];
        const float4 v10 = s4[o.z + c4];
        const float4 v11 = s4[o.w + c4];
        float4 r;
        r.x = w.x * v00.x + w.y * v01.x + w.z * v10.x + w.w * v11.x;
        r.y = w.x * v00.y + w.y * v01.y + w.z * v10.y + w.w * v11.y;
        r.z = w.x * v00.z + w.y * v01.z + w.z * v10.z + w.w * v11.z;
        r.w = w.x * v00.w + w.y * v01.w + w.z * v10.w + w.w * v11.w;
        o4[pos * 128 + c4] = r;
    }
}

// ---------------------------------------------------------------------------
extern "C" void kernel_launch(void* const* d_in, const int* in_sizes, int n_in,
                              void* d_out, int out_size, void* d_ws, size_t ws_size,
                              hipStream_t stream)
{
    const float* t0  = (const float*)d_in[0];
    const float* t1  = (const float*)d_in[1];
    const float* w1  = (const float*)d_in[2];
    const float* b1  = (const float*)d_in[3];
    const float* w2  = (const float*)d_in[4];
    const float* b2  = (const float*)d_in[5];
    const float* dw1 = (const float*)d_in[6];
    const float* db1 = (const float*)d_in[7];
    const float* dw2 = (const float*)d_in[8];
    const float* db2 = (const float*)d_in[9];
    const float* cb  = (const float*)d_in[10];

    float* out = (float*)d_out;
    float* ws  = (float*)d_ws;

    float* pooled = ws;                  // 2048*128   = 262144 floats
    float* dec    = ws + 262144;         // 2048*512   = 1048576 floats
    float* hist   = ws + 1310720;        // 256
    float* commit = ws + 1310976;        // 1

    // Bt hi/lo (bf16, 64K elems each) alias the dec region: k0/k1 finish
    // before k2 writes dec.
    unsigned short* bth = (unsigned short*)(ws + 262144);
    unsigned short* btl = (unsigned short*)(ws + 262144 + 32768);

    hipMemsetAsync(hist, 0, 257 * sizeof(float), stream);

    k0_prep_w1<<<32, 256, 0, stream>>>(w1, bth, btl);
    k1_enc_pool<<<512, 256, 0, stream>>>(t0, t1, bth, btl, b1, pooled);
    k2_mid<<<512, 256, 0, stream>>>(pooled, w2, b2, cb, dw1, db1, dw2, db2,
                                    dec, hist, commit, out + DECODED_SZ + 2);
    k2b_final<<<1, 256, 0, stream>>>(hist, commit, out + DECODED_SZ);
    k3_upsample<<<512, 256, 0, stream>>>(dec, out);
}

// Round 2
// 601.411 us; speedup vs baseline: 1.0520x; 1.0520x over previous
//
#include <hip/hip_runtime.h>
#include <math.h>

// B=512, H=W=14, DIN=512, EDIM=64, K=256, GRID=2 -> 2048 tokens, 128 hidden
#define N_TOKENS   2048
#define DECODED_SZ 51380224   // 512*14*14*512
// d_out layout: [decoded (51380224)][perplexity (1)][commitment (1)][indices (2048)]

typedef __attribute__((ext_vector_type(8)))  short bf16x8;
typedef __attribute__((ext_vector_type(16))) float f32x16;

__device__ __forceinline__ float gelu_exact(float x) {
    return 0.5f * x * (1.0f + erff(x * 0.70710678118654752440f));
}

// round-to-nearest-even fp32 -> bf16 bits
__device__ __forceinline__ unsigned int f2bf(float x) {
    unsigned int u = __float_as_uint(x);
    return (u + 0x7fffu + ((u >> 16) & 1u)) >> 16;
}
__device__ __forceinline__ float bf2f(unsigned int b) {
    return __uint_as_float(b << 16);
}

// packed fp32x2 -> bf16x2 (lo=src0, hi=src1), RNE via HW
__device__ __forceinline__ unsigned int cvt_pk_bf16(float a, float b) {
    unsigned int p;
    asm("v_cvt_pk_bf16_f32 %0, %1, %2" : "=v"(p) : "v"(a), "v"(b));
    return p;
}
// split pair into hi word + lo(residual) word
__device__ __forceinline__ void split_pair(float a, float b,
                                           unsigned int& hi, unsigned int& lo) {
    hi = cvt_pk_bf16(a, b);
    const float ra = a - __uint_as_float(hi << 16);
    const float rb = b - __uint_as_float(hi & 0xffff0000u);
    lo = cvt_pk_bf16(ra, rb);
}

// ---------------------------------------------------------------------------
// K0: split w1 [512k x 128n] fp32 into bf16 hi/lo, transposed + k-chunk-blocked
// + XOR-swizzled at 16B-slot granularity (slot ^= col&3) so that k1's LDS
// fragment reads are bank-conflict-free after a LINEAR global->LDS copy.
// Layout: Bt[kc(16)][n(128)][slot(4)^swz][8 bf16].
// ---------------------------------------------------------------------------
__global__ __launch_bounds__(256) void k0_prep_w1(
    const float* __restrict__ w1,
    unsigned short* __restrict__ bth, unsigned short* __restrict__ btl)
{
    const int i  = blockIdx.x * 256 + threadIdx.x;   // 0..8191
    const int n  = i >> 6;
    const int kg = i & 63;
    const int k0i = kg * 8;

    unsigned int h[8], lo[8];
#pragma unroll
    for (int j = 0; j < 8; ++j) {
        float v = w1[(k0i + j) * 128 + n];
        h[j]  = f2bf(v);
        lo[j] = f2bf(v - bf2f(h[j]));
    }
    const int s   = (k0i & 31) >> 3;                 // 16B slot within 32-k chunk
    const int idx = (k0i >> 5) * 4096 + n * 32 + 8 * (s ^ (n & 3));
    uint4 hv, lv;
    hv.x = h[0]  | (h[1] << 16);  hv.y = h[2]  | (h[3] << 16);
    hv.z = h[4]  | (h[5] << 16);  hv.w = h[6]  | (h[7] << 16);
    lv.x = lo[0] | (lo[1] << 16); lv.y = lo[2] | (lo[3] << 16);
    lv.z = lo[4] | (lo[5] << 16); lv.w = lo[6] | (lo[7] << 16);
    *reinterpret_cast<uint4*>(bth + idx) = hv;
    *reinterpret_cast<uint4*>(btl + idx) = lv;
}

// ---------------------------------------------------------------------------
// K1 (v3): half-image blocks, coalesced LDS staging, issue-early pipeline.
// grid 1024 x 512 thr (8 waves). Block bid: image b=bid>>1, half=bid&1,
// rows [half*128, +128) (padded/clamped past row 195).
// Wave w: wm=w>>1 -> local M-tile (32 rows), wn=w&1 -> N half (64 cols).
// Per kc (K-chunk of 32):
//   - A: 128x32 fp32 delta, loaded lane-linear (fully coalesced), split to
//     bf16 hi/lo in-reg (cvt_pk), stored to LDS with 16B-slot XOR swizzle.
//   - B: linear 16B/lane copy of pre-swizzled bth/btl slab.
//   - 1 barrier/kc, double-buffered LDS; loads for kc+1 issued right after
//     the barrier, in flight across the whole MFMA phase (T14).
// Output: per-block PARTIAL token sums -> part[bid][4][128] (k2 combines).
// ---------------------------------------------------------------------------
__global__ __launch_bounds__(512, 4) void k1_enc_pool(
    const float* __restrict__ t0, const float* __restrict__ t1,
    const unsigned short* __restrict__ bth, const unsigned short* __restrict__ btl,
    const float* __restrict__ b1,
    float* __restrict__ part)
{
    __shared__ unsigned short sAh[2][4096];   // 16 KB
    __shared__ unsigned short sAl[2][4096];   // 16 KB
    __shared__ unsigned short sBh[2][4096];   // 16 KB
    __shared__ unsigned short sBl[2][4096];   // 16 KB
    __shared__ float sR[4][4][128];           //  8 KB  -> 72 KB total, 2 blk/CU

    const int t    = threadIdx.x;             // 0..511
    const int bid  = blockIdx.x;              // 0..1023
    const int b    = bid >> 1;
    const int half = bid & 1;
    const int l     = t & 63;
    const int w     = t >> 6;
    const int wm    = w >> 1;
    const int wn    = w & 1;
    const int lan31 = l & 31;
    const int h     = l >> 5;

    const float4* __restrict__ t0v = reinterpret_cast<const float4*>(t0);
    const float4* __restrict__ t1v = reinterpret_cast<const float4*>(t1);

    // ---- A staging addresses: item j covers float4 f of local row r
    int aG[2], aW[2];
#pragma unroll
    for (int j = 0; j < 2; ++j) {
        const int i = t + j * 512;            // 0..1023 = 128 rows x 8 f4
        const int r = i >> 3, f = i & 7;
        const int rg = b * 196 + min(half * 128 + r, 195);   // clamp tail rows
        aG[j] = rg * 128 + f;                                // float4 units
        aW[j] = r * 32 + 8 * ((f >> 1) ^ (r & 3)) + 4 * (f & 1); // ushort units
    }
    const int bG = t * 8;                     // ushort units within a kc slab

    // ---- fragment read offsets (swizzled, conflict-free)
    int arOff[2], brOff[2][2];
    {
        const int r = wm * 32 + lan31;
#pragma unroll
        for (int ks = 0; ks < 2; ++ks)
            arOff[ks] = r * 32 + 8 * ((2 * ks + h) ^ (r & 3));
#pragma unroll
        for (int ni = 0; ni < 2; ++ni) {
            const int c = (wn * 2 + ni) * 32 + lan31;
#pragma unroll
            for (int ks = 0; ks < 2; ++ks)
                brOff[ni][ks] = c * 32 + 8 * ((2 * ks + h) ^ (c & 3));
        }
    }
    const bool tile_ok = (half * 4 + wm) < 7;  // global M-tile 7 is all padding

    f32x16 acc[2] = {};

    float4 p0a, p0b, p1a, p1b;                 // A prefetch (t0/t1, items 0/1)
    uint4  qh, ql;                             // B prefetch

    // prologue: loads for kc=0
    p1a = t1v[aG[0]]; p0a = t0v[aG[0]];
    p1b = t1v[aG[1]]; p0b = t0v[aG[1]];
    qh = *reinterpret_cast<const uint4*>(bth + bG);
    ql = *reinterpret_cast<const uint4*>(btl + bG);

#pragma unroll 2
    for (int kc = 0; kc < 16; ++kc) {
        unsigned short* __restrict__ ah = sAh[kc & 1];
        unsigned short* __restrict__ al = sAl[kc & 1];
        unsigned short* __restrict__ bh = sBh[kc & 1];
        unsigned short* __restrict__ bl = sBl[kc & 1];

        // ---- write staged data (implicit vmcnt wait on p/q only)
        {
            unsigned int h0, l0, h1, l1;
            split_pair(p1a.x - p0a.x, p1a.y - p0a.y, h0, l0);
            split_pair(p1a.z - p0a.z, p1a.w - p0a.w, h1, l1);
            *reinterpret_cast<uint2*>(ah + aW[0]) = make_uint2(h0, h1);
            *reinterpret_cast<uint2*>(al + aW[0]) = make_uint2(l0, l1);
            split_pair(p1b.x - p0b.x, p1b.y - p0b.y, h0, l0);
            split_pair(p1b.z - p0b.z, p1b.w - p0b.w, h1, l1);
            *reinterpret_cast<uint2*>(ah + aW[1]) = make_uint2(h0, h1);
            *reinterpret_cast<uint2*>(al + aW[1]) = make_uint2(l0, l1);
            *reinterpret_cast<uint4*>(bh + bG) = qh;
            *reinterpret_cast<uint4*>(bl + bG) = ql;
        }
        __syncthreads();

        // ---- prefetch kc+1 (in flight across the MFMA phase below)
        if (kc < 15) {
            const int g = (kc + 1) * 8;
            p1a = t1v[aG[0] + g]; p0a = t0v[aG[0] + g];
            p1b = t1v[aG[1] + g]; p0b = t0v[aG[1] + g];
            const int bg2 = (kc + 1) * 4096 + bG;
            qh = *reinterpret_cast<const uint4*>(bth + bg2);
            ql = *reinterpret_cast<const uint4*>(btl + bg2);
        }
        __builtin_amdgcn_sched_barrier(0);    // keep prefetch issued early

        // ---- compute kc
        if (tile_ok) {
#pragma unroll
            for (int ks = 0; ks < 2; ++ks) {
                const bf16x8 fah = *reinterpret_cast<const bf16x8*>(ah + arOff[ks]);
                const bf16x8 fal = *reinterpret_cast<const bf16x8*>(al + arOff[ks]);
#pragma unroll
                for (int ni = 0; ni < 2; ++ni) {
                    const bf16x8 fbh = *reinterpret_cast<const bf16x8*>(bh + brOff[ni][ks]);
                    const bf16x8 fbl = *reinterpret_cast<const bf16x8*>(bl + brOff[ni][ks]);
                    acc[ni] = __builtin_amdgcn_mfma_f32_32x32x16_bf16(
                        fah, fbh, acc[ni], 0, 0, 0);
                    acc[ni] = __builtin_amdgcn_mfma_f32_32x32x16_bf16(
                        fah, fbl, acc[ni], 0, 0, 0);
                    acc[ni] = __builtin_amdgcn_mfma_f32_32x32x16_bf16(
                        fal, fbh, acc[ni], 0, 0, 0);
                }
            }
        }
    }

    // ---- epilogue: bias + gelu + partial pool per token, per lane
    float tokacc[2][4] = {};
#pragma unroll
    for (int ni = 0; ni < 2; ++ni) {
        const int col = (wn * 2 + ni) * 32 + lan31;
        const float bias = b1[col];
#pragma unroll
        for (int reg = 0; reg < 16; ++reg) {
            const int rl = wm * 32 + (reg & 3) + 8 * (reg >> 2) + 4 * h;
            const int rg = half * 128 + rl;
            if (rg < 196) {
                const float v = gelu_exact(acc[ni][reg] + bias);
                const int py = rg / 14, px = rg % 14;
                const int tok = ((py >= 7) ? 2 : 0) + ((px >= 7) ? 1 : 0);
                tokacc[ni][tok] += v;
            }
        }
    }
    // fold h=1 lanes into h=0 lanes
#pragma unroll
    for (int ni = 0; ni < 2; ++ni)
#pragma unroll
        for (int tok = 0; tok < 4; ++tok)
            tokacc[ni][tok] += __shfl_xor(tokacc[ni][tok], 32);
    if (h == 0) {
#pragma unroll
        for (int ni = 0; ni < 2; ++ni)
#pragma unroll
            for (int tok = 0; tok < 4; ++tok)
                sR[wm][tok][wn * 64 + ni * 32 + lan31] = tokacc[ni][tok];
    }
    __syncthreads();
    {
        const int tok = t >> 7, col = t & 127;
        part[bid * 512 + tok * 128 + col] =
            sR[0][tok][col] + sR[1][tok][col] + sR[2][tok][col] + sR[3][tok][col];
    }
}

// ---------------------------------------------------------------------------
// K2: per-token middle. 512 blocks x 256 thr, 4 tokens/block.
// Combines the two half-image partials (deterministic) + scales by 1/49.
// Codebook staged in LDS (stride 66 -> conflict-free float2 reads).
// ---------------------------------------------------------------------------
__global__ __launch_bounds__(256, 2) void k2_mid(
    const float* __restrict__ part,
    const float* __restrict__ w2,  const float* __restrict__ b2,
    const float* __restrict__ cb,
    const float* __restrict__ dw1, const float* __restrict__ db1,
    const float* __restrict__ dw2, const float* __restrict__ db2,
    float* __restrict__ dec, float* __restrict__ hist, float* __restrict__ commit,
    float* __restrict__ out_idx)
{
    __shared__ float sCB[256 * 66];  // 67.6 KB codebook, padded stride
    __shared__ float ph[4 * 128];
    __shared__ float es[4 * 64];
    __shared__ float hd[4 * 128];
    __shared__ float rd[256];
    __shared__ int   ri[256];
    __shared__ int   idxs[4];
    __shared__ float dms[4];

    const int t   = threadIdx.x;
    const int tk0 = blockIdx.x * 4;

    if (t < 128) {
        const float4 x = reinterpret_cast<const float4*>(
            part + (blockIdx.x * 2 + 0) * 512)[t];
        const float4 y = reinterpret_cast<const float4*>(
            part + (blockIdx.x * 2 + 1) * 512)[t];
        float4 s;
        s.x = (x.x + y.x) * (1.0f / 49.0f);
        s.y = (x.y + y.y) * (1.0f / 49.0f);
        s.z = (x.z + y.z) * (1.0f / 49.0f);
        s.w = (x.w + y.w) * (1.0f / 49.0f);
        reinterpret_cast<float4*>(ph)[t] = s;
    }
    for (int i = t; i < 16384; i += 256) {
        int row = i >> 6, k = i & 63;
        sCB[row * 66 + k] = cb[i];
    }
    __syncthreads();

    // e = ph @ w2 + b2   (j = t&63, one token per 64-lane group)
    {
        const int j = t & 63, tok = t >> 6;
        float a = b2[j];
        const float* phr = ph + tok * 128;
#pragma unroll 8
        for (int k = 0; k < 128; ++k)
            a = fmaf(phr[k], w2[k * 64 + j], a);
        es[tok * 64 + j] = a;
    }
    __syncthreads();

    // VQ: 64 threads/token, 4 strided codes each; explicit index tiebreak
    {
        const int tok = t >> 6, c8 = t & 63;
        float2 ev[32];
#pragma unroll
        for (int k = 0; k < 32; ++k)
            ev[k] = *reinterpret_cast<const float2*>(es + tok * 64 + 2 * k);
        float dmin = 3.4e38f; int imin = 0;
#pragma unroll
        for (int cc = 0; cc < 4; ++cc) {
            const int c = c8 + cc * 64;
            const float* cr = sCB + c * 66;
            float d = 0.f;
#pragma unroll
            for (int k = 0; k < 32; ++k) {
                float2 c2 = *reinterpret_cast<const float2*>(cr + 2 * k);
                float d0 = ev[k].x - c2.x;
                float d1 = ev[k].y - c2.y;
                d = fmaf(d0, d0, d);
                d = fmaf(d1, d1, d);
            }
            if (d < dmin || (d == dmin && c < imin)) { dmin = d; imin = c; }
        }
        rd[t] = dmin; ri[t] = imin;
    }
    __syncthreads();
    for (int s = 32; s > 0; s >>= 1) {
        if ((t & 63) < s) {
            float dn = rd[t + s]; int in = ri[t + s];
            if (dn < rd[t] || (dn == rd[t] && in < ri[t])) { rd[t] = dn; ri[t] = in; }
        }
        __syncthreads();
    }
    if ((t & 63) == 0) {
        const int tok = t >> 6;
        idxs[tok] = ri[t];
        dms[tok]  = rd[t];
        out_idx[tk0 + tok] = (float)ri[t];
        atomicAdd(&hist[ri[t]], 1.0f);
    }
    __syncthreads();
    if (t == 0) {
        float s = dms[0] + dms[1] + dms[2] + dms[3];
        atomicAdd(commit, s);
    }

    // hd = gelu(q @ dw1 + db1), q read straight from sCB
    {
        const int j = t & 127, half = t >> 7;
        const float bj = db1[j];
        float a0 = bj, a1 = bj;
        const float* q0 = sCB + idxs[half * 2 + 0] * 66;
        const float* q1 = sCB + idxs[half * 2 + 1] * 66;
#pragma unroll 4
        for (int k = 0; k < 64; ++k) {
            const float wv = dw1[k * 128 + j];
            a0 = fmaf(q0[k], wv, a0);
            a1 = fmaf(q1[k], wv, a1);
        }
        hd[(half * 2 + 0) * 128 + j] = gelu_exact(a0);
        hd[(half * 2 + 1) * 128 + j] = gelu_exact(a1);
    }
    __syncthreads();

    // dec = hd @ dw2 + db2  (each thread: cols t and t+256, all 4 tokens)
    {
        float a0[4], a1[4];
        const float bb0 = db2[t], bb1 = db2[t + 256];
#pragma unroll
        for (int q = 0; q < 4; ++q) { a0[q] = bb0; a1[q] = bb1; }
#pragma unroll 2
        for (int j = 0; j < 128; ++j) {
            const float w0 = dw2[j * 512 + t];
            const float w1v = dw2[j * 512 + 256 + t];
#pragma unroll
            for (int q = 0; q < 4; ++q) {
                const float h = hd[q * 128 + j];
                a0[q] = fmaf(h, w0, a0[q]);
                a1[q] = fmaf(h, w1v, a1[q]);
            }
        }
#pragma unroll
        for (int q = 0; q < 4; ++q) {
            dec[(tk0 + q) * 512 + t]       = a0[q];
            dec[(tk0 + q) * 512 + 256 + t] = a1[q];
        }
    }
}

// ---------------------------------------------------------------------------
// K2b: finalize perplexity + commitment (1 block)
// ---------------------------------------------------------------------------
__global__ __launch_bounds__(256) void k2b_final(
    const float* __restrict__ hist, const float* __restrict__ commit,
    float* __restrict__ out2)
{
    __shared__ float red[256];
    const int t = threadIdx.x;
    float p = hist[t] * (1.0f / 2048.0f);
    red[t] = p * logf(p + 1e-10f);
    __syncthreads();
    for (int s = 128; s > 0; s >>= 1) {
        if (t < s) red[t] += red[t + s];
        __syncthreads();
    }
    if (t == 0) {
        out2[0] = expf(-red[0]);
        out2[1] = commit[0] * (1.0f / 131072.0f);   // /(2048*64)
    }
}

// ---------------------------------------------------------------------------
// K3: bilinear upsample dec[B,2,2,512] -> decoded[B,14,14,512]
// Weights/offsets precomputed once per block into LDS.
// ---------------------------------------------------------------------------
__global__ __launch_bounds__(256, 4) void k3_upsample(
    const float* __restrict__ dec, float* __restrict__ out)
{
    __shared__ float  sdec[4 * 512];
    __shared__ float4 wts[196];
    __shared__ int4   offs[196];
    const int b = blockIdx.x, t = threadIdx.x;

    for (int i = t; i < 512; i += 256)
        reinterpret_cast<float4*>(sdec)[i] =
            reinterpret_cast<const float4*>(dec + b * 2048)[i];
    if (t < 196) {
        const int y = t / 14, x = t % 14;
        const float sy = (y + 0.5f) * (1.0f / 7.0f) - 0.5f;
        const float sx = (x + 0.5f) * (1.0f / 7.0f) - 0.5f;
        const int iy = (int)floorf(sy), ix = (int)floorf(sx);
        const float fy = sy - (float)iy, fx = sx - (float)ix;
        const int y0 = min(max(iy, 0), 1), y1 = min(max(iy + 1, 0), 1);
        const int x0 = min(max(ix, 0), 1), x1 = min(max(ix + 1, 0), 1);
        float4 w;
        w.x = (1.f - fy) * (1.f - fx); w.y = (1.f - fy) * fx;
        w.z = fy * (1.f - fx);         w.w = fy * fx;
        wts[t] = w;
        int4 o;
        o.x = (y0 * 2 + x0) * 128; o.y = (y0 * 2 + x1) * 128;
        o.z = (y1 * 2 + x0) * 128; o.w = (y1 * 2 + x1) * 128;
        offs[t] = o;
    }
    __syncthreads();

    const float4* s4 = reinterpret_cast<const float4*>(sdec);
    float4* o4 = reinterpret_cast<float4*>(out) + b * 25088;
    const int c4 = t & 127, ph2 = t >> 7;

#pragma unroll 2
    for (int it = 0; it < 98; ++it) {
        const int pos = ph2 + it * 2;
        const float4 w = wts[pos];
        const int4   o = offs[pos];
        const float4 v00 = s4[o.x + c4];
        const float4 v01 = s4[o.y + c4];
        const float4 v10 = s4[o.z + c4];
        const float4 v11 = s4[o.w + c4];
        float4 r;
        r.x = w.x * v00.x + w.y * v01.x + w.z * v10.x + w.w * v11.x;
        r.y = w.x * v00.y + w.y * v01.y + w.z * v10.y + w.w * v11.y;
        r.z = w.x * v00.z + w.y * v01.z + w.z * v10.z + w.w * v11.z;
        r.w = w.x * v00.w + w.y * v01.w + w.z * v10.w + w.w * v11.w;
        o4[pos * 128 + c4] = r;
    }
}

// ---------------------------------------------------------------------------
extern "C" void kernel_launch(void* const* d_in, const int* in_sizes, int n_in,
                              void* d_out, int out_size, void* d_ws, size_t ws_size,
                              hipStream_t stream)
{
    const float* t0  = (const float*)d_in[0];
    const float* t1  = (const float*)d_in[1];
    const float* w1  = (const float*)d_in[2];
    const float* b1  = (const float*)d_in[3];
    const float* w2  = (const float*)d_in[4];
    const float* b2  = (const float*)d_in[5];
    const float* dw1 = (const float*)d_in[6];
    const float* db1 = (const float*)d_in[7];
    const float* dw2 = (const float*)d_in[8];
    const float* db2 = (const float*)d_in[9];
    const float* cb  = (const float*)d_in[10];

    float* out = (float*)d_out;
    float* ws  = (float*)d_ws;

    float* part   = ws;                  // 1024*512   = 524288 floats
    float* dec    = ws + 524288;         // 2048*512   = 1048576 floats
    float* hist   = ws + 1572864;        // 256
    float* commit = ws + 1573120;        // 1

    // Bt hi/lo (bf16, 64K elems each) alias the dec region: k0/k1 finish
    // before k2 writes dec.
    unsigned short* bth = (unsigned short*)(ws + 524288);
    unsigned short* btl = (unsigned short*)(ws + 524288 + 32768);

    hipMemsetAsync(hist, 0, 257 * sizeof(float), stream);

    k0_prep_w1<<<32, 256, 0, stream>>>(w1, bth, btl);
    k1_enc_pool<<<1024, 512, 0, stream>>>(t0, t1, bth, btl, b1, part);
    k2_mid<<<512, 256, 0, stream>>>(part, w2, b2, cb, dw1, db1, dw2, db2,
                                    dec, hist, commit, out + DECODED_SZ + 2);
    k2b_final<<<1, 256, 0, stream>>>(hist, commit, out + DECODED_SZ);
    k3_upsample<<<512, 256, 0, stream>>>(dec, out);
}